// Round 8
// baseline (160.975 us; speedup 1.0000x reference)
//
#include <hip/hip_runtime.h>

#define HIDDEN   2048
#define GROWS    6144            // 3 * HIDDEN
#define VOCAB    53
#define LAYERS   6
#define NBLK     512             // 2 blocks/CU -> all co-resident
#define NWAVE    4
#define NT       256             // 4 waves; each wave owns one output j
#define SUB_LINES   32
#define BLK_PER_SUB (NBLK / SUB_LINES)   // 16

// ws layout (bytes):
//   [0, 49152)       float h_work[6][2048]  (relaxed bypass atomics only)
//   [49152, 61440)   per layer: 32 sub-counters, 64B apart
#define WS_H_OFF     0
#define WS_SUB_OFF   49152
#define WS_CTR_BYTES (SUB_LINES * 64 * LAYERS)

typedef unsigned long long ull;

#define VMCNT0 asm volatile("s_waitcnt vmcnt(0)" ::: "memory")

// Persistent fused GRU stack. R6's proven relaxed-atomic message-passing
// (no acquire/release fences -> no whole-L2 wb/inv), with the per-layer
// critical path shortened: wave-owns-j (no gate funnel), direct 32-lane
// ballot poll of sub-counters (no master hop), LDS-atomic last-wave bump.
__global__ __launch_bounds__(NT, 2) void gru_fused(
    const int*   __restrict__ token,
    const float* __restrict__ hidden,   // [6][2048]
    const float* __restrict__ emb,      // [53][2048]
    const float* __restrict__ w_ih,     // [6][6144][2048]
    const float* __restrict__ w_hh,     // [6][6144][2048]
    const float* __restrict__ b_ih,     // [6][6144]
    const float* __restrict__ b_hh,     // [6][6144]
    const float* __restrict__ w_dec,    // [53][2048]
    const float* __restrict__ b_dec,    // [53]
    float*       __restrict__ out,      // [53 logits][6*2048 h_new]
    char*        __restrict__ ws)
{
    const int bid  = blockIdx.x;
    const int tid  = threadIdx.x;
    const int wave = tid >> 6;
    const int lane = tid & 63;
    const int j    = bid * NWAVE + wave;     // this wave's output element

    float*    h_work = (float*)(ws + WS_H_OFF);
    unsigned* subc   = (unsigned*)(ws + WS_SUB_OFF);

    __shared__ float    xlds[HIDDEN];        // 8 KB staged x
    __shared__ unsigned done[LAYERS];
    if (tid < LAYERS) done[tid] = 0;
    __syncthreads();

    const float* x0 = emb + (size_t)token[0] * HIDDEN;

    for (int l = 0; l < LAYERS; ++l) {
        const float* Whh = w_hh + (size_t)l * GROWS * HIDDEN;
        const float* Wih = w_ih + (size_t)l * GROWS * HIDDEN;

        // hidden[l] fragment (input array -> plain cached loads)
        float4 hv[8];
        {
            const float4* hs = (const float4*)(hidden + (size_t)l * HIDDEN);
            #pragma unroll
            for (int u = 0; u < 8; ++u) hv[u] = hs[u * 64 + lane];
        }

        // ---- phase A: 3 w_hh-row dots (chain-independent; streams pre-poll) ----
        float ah[3];
        #pragma unroll
        for (int gt = 0; gt < 3; ++gt) {
            const float4* W = (const float4*)(Whh + ((size_t)gt * HIDDEN + j) * HIDDEN);
            float s = 0.f;
            #pragma unroll
            for (int u = 0; u < 8; ++u) {
                float4 w4 = W[u * 64 + lane];
                s += w4.x * hv[u].x + w4.y * hv[u].y + w4.z * hv[u].z + w4.w * hv[u].w;
            }
            ah[gt] = s;
        }

        // ---- prefetch 3 w_ih rows into registers (consumed post-poll) ----
        float4 wf[3][8];
        #pragma unroll
        for (int gt = 0; gt < 3; ++gt) {
            const float4* W = (const float4*)(Wih + ((size_t)gt * HIDDEN + j) * HIDDEN);
            #pragma unroll
            for (int u = 0; u < 8; ++u) wf[gt][u] = W[u * 64 + lane];
        }

        // ---- poll: 32 lanes watch layer l-1's 32 sub-counters directly ----
        if (l > 0 && wave == 0) {
            const unsigned* sc = subc + (size_t)(l - 1) * SUB_LINES * 16;
            for (;;) {
                unsigned c = BLK_PER_SUB;
                if (lane < SUB_LINES)
                    c = __hip_atomic_load(&sc[lane * 16], __ATOMIC_RELAXED,
                                          __HIP_MEMORY_SCOPE_AGENT);
                if (__all(c >= BLK_PER_SUB)) break;
                __builtin_amdgcn_s_sleep(1);
            }
        }
        __syncthreads();

        // ---- stage x into LDS (bypass loads: producer stored bypass) ----
        if (l == 0) {
            const float4* xs = (const float4*)x0;
            #pragma unroll
            for (int i = 0; i < 2; ++i)
                ((float4*)xlds)[tid + i * NT] = xs[tid + i * NT];
        } else {
            const ull* hsrc = (const ull*)(h_work + (size_t)(l - 1) * HIDDEN);
            #pragma unroll
            for (int i = 0; i < 4; ++i)
                ((ull*)xlds)[tid + i * NT] =
                    __hip_atomic_load(&hsrc[tid + i * NT], __ATOMIC_RELAXED,
                                      __HIP_MEMORY_SCOPE_AGENT);
        }
        __syncthreads();

        // ---- phase C: 3 w_ih-row dots, registers x LDS (no HBM traffic) ----
        float ai[3];
        {
            const float4* xl = (const float4*)xlds;
            float4 xv[8];
            #pragma unroll
            for (int u = 0; u < 8; ++u) xv[u] = xl[u * 64 + lane];
            #pragma unroll
            for (int gt = 0; gt < 3; ++gt) {
                float s = 0.f;
                #pragma unroll
                for (int u = 0; u < 8; ++u)
                    s += wf[gt][u].x * xv[u].x + wf[gt][u].y * xv[u].y
                       + wf[gt][u].z * xv[u].z + wf[gt][u].w * xv[u].w;
                ai[gt] = s;
            }
        }

        // ---- wave-local reduce of all 6 sums (ILP'd butterfly) ----
        #pragma unroll
        for (int o = 32; o; o >>= 1) {
            ah[0] += __shfl_down(ah[0], o, 64);
            ah[1] += __shfl_down(ah[1], o, 64);
            ah[2] += __shfl_down(ah[2], o, 64);
            ai[0] += __shfl_down(ai[0], o, 64);
            ai[1] += __shfl_down(ai[1], o, 64);
            ai[2] += __shfl_down(ai[2], o, 64);
        }

        // ---- gates + publish (each wave's lane 0; no cross-wave funnel) ----
        if (lane == 0) {
            const float* bi = b_ih + (size_t)l * GROWS;
            const float* bh = b_hh + (size_t)l * GROWS;
            float gir = ai[0] + bi[j];
            float giz = ai[1] + bi[j + HIDDEN];
            float gin = ai[2] + bi[j + 2 * HIDDEN];
            float ghr = ah[0] + bh[j];
            float ghz = ah[1] + bh[j + HIDDEN];
            float ghn = ah[2] + bh[j + 2 * HIDDEN];
            float r = 1.f / (1.f + __expf(-(gir + ghr)));
            float z = 1.f / (1.f + __expf(-(giz + ghz)));
            float n = tanhf(gin + r * ghn);
            float hvv = (1.f - z) * n + z * hidden[(size_t)l * HIDDEN + j];
            __hip_atomic_store(&h_work[(size_t)l * HIDDEN + j], hvv,
                               __ATOMIC_RELAXED, __HIP_MEMORY_SCOPE_AGENT);
            out[VOCAB + (size_t)l * HIDDEN + j] = hvv;
        }
        VMCNT0;   // wave-level: h store performed at coherence point
        if (lane == 0) {
            unsigned old = atomicAdd(&done[l], 1u);     // LDS, CU-local
            if (old == NWAVE - 1)                       // last wave: signal
                __hip_atomic_fetch_add(
                    &subc[((size_t)l * SUB_LINES + (bid & (SUB_LINES - 1))) * 16],
                    1u, __ATOMIC_RELAXED, __HIP_MEMORY_SCOPE_AGENT);
        }
        // No trailing barrier needed: xlds is next written only after the
        // next poll's __syncthreads, which every wave reaches only after
        // finishing its phase-C reads of xlds.
    }

    // ---- decode: logits = w_dec @ h[5] + b_dec (blocks 0..52) ----
    if (bid < VOCAB) {
        if (wave == 0) {
            const unsigned* sc = subc + (size_t)(LAYERS - 1) * SUB_LINES * 16;
            for (;;) {
                unsigned c = BLK_PER_SUB;
                if (lane < SUB_LINES)
                    c = __hip_atomic_load(&sc[lane * 16], __ATOMIC_RELAXED,
                                          __HIP_MEMORY_SCOPE_AGENT);
                if (__all(c >= BLK_PER_SUB)) break;
                __builtin_amdgcn_s_sleep(1);
            }
        }
        __syncthreads();
        {
            const ull* hsrc = (const ull*)(h_work + (size_t)(LAYERS - 1) * HIDDEN);
            #pragma unroll
            for (int i = 0; i < 4; ++i)
                ((ull*)xlds)[tid + i * NT] =
                    __hip_atomic_load(&hsrc[tid + i * NT], __ATOMIC_RELAXED,
                                      __HIP_MEMORY_SCOPE_AGENT);
        }
        __syncthreads();
        const float4* W  = (const float4*)(w_dec + (size_t)bid * HIDDEN);
        const float4* xl = (const float4*)xlds;
        float s = 0.f;
        #pragma unroll
        for (int i = 0; i < 2; ++i) {
            float4 a = W[tid + i * NT];
            float4 b = xl[tid + i * NT];
            s += a.x * b.x + a.y * b.y + a.z * b.z + a.w * b.w;
        }
        #pragma unroll
        for (int o = 32; o; o >>= 1) s += __shfl_down(s, o, 64);
        __shared__ float dred[NWAVE];
        if (lane == 0) dred[wave] = s;
        __syncthreads();
        if (tid == 0)
            out[bid] = dred[0] + dred[1] + dred[2] + dred[3] + b_dec[bid];
    }
}

extern "C" void kernel_launch(void* const* d_in, const int* in_sizes, int n_in,
                              void* d_out, int out_size, void* d_ws, size_t ws_size,
                              hipStream_t stream) {
    const int*   token  = (const int*)  d_in[0];
    const float* hidden = (const float*)d_in[1];
    const float* emb    = (const float*)d_in[2];
    const float* w_ih   = (const float*)d_in[3];
    const float* w_hh   = (const float*)d_in[4];
    const float* b_ih   = (const float*)d_in[5];
    const float* b_hh   = (const float*)d_in[6];
    const float* w_dec  = (const float*)d_in[7];
    const float* b_dec  = (const float*)d_in[8];

    float* out = (float*)d_out;
    char*  ws  = (char*)d_ws;

    // zero the barrier counters (graph replays reuse ws)
    (void)hipMemsetAsync(ws + WS_SUB_OFF, 0, WS_CTR_BYTES, stream);

    gru_fused<<<dim3(NBLK), dim3(NT), 0, stream>>>(
        token, hidden, emb, w_ih, w_hh, b_ih, b_hh,
        w_dec, b_dec, out, ws);
}